// Round 5
// baseline (101.038 us; speedup 1.0000x reference)
//
#include <hip/hip_runtime.h>
#include <hip/hip_bf16.h>

// ---------------------------------------------------------------------------
// preds[i][c] = sum_j exp(cos(e_i, t_j)) [y_j==c]  /  sum_j exp(cos(e_i, t_j))
// where e = normalize(mlp(X)), t = normalize(mlp(x_train)).
// exp needs no max-subtraction: cosine <= 1 so exp(s) <= e.
//
// R5 = R4 with the compile fix: __builtin_amdgcn_cvt_pkrtz returns
// __fp16x2, so the pack union uses __fp16 elements (bit-identical storage).
//
// R4 changes vs R3:
//  * BUGFIX: R3 used fbase = wstart>>4 (tile idx) as a FRAG index (frag =
//    tile*2). S-side read wrong train tiles; only passed because exp(cos)
//    weights are tightly concentrated. Now indexed per-group: frag = t32>>3.
//  * Whole pipeline in f16 (mfma_f32_16x16x32_f16): more mantissa than bf16,
//    and P packs via full-rate v_cvt_pkrtz_f16_f32 (no perms, no RNE adds).
//  * k_main: TM=64, TS=16, launch_bounds(256,3) -> 12 waves/CU latency
//    hiding; no explicit prefetch; output via LDS combine + atomicAdd.
//  * k_prep (64 blocks): W1/W2 -> f16 frags ONCE, permuted f16 V-frags,
//    zeroes acc.
//
// Frag-ready layout for an f16 matrix M[row][k] (16-row tiles, K=64):
//   elem(row,k) at ((row>>4)*2 + (k>>5))*512 + (((k>>3)&3)*16 + (row&15))*8
//                + (k&7);  one frag = 512 elems; load = dwordx4 at lane*8.
//   Serves both A-operands (row=M) and B-operands (row=N).
// PV direct-feed permutation: V stored with k-index tau(quad,j) =
//   (j>>2)*16 + quad*4 + (j&3) so the S^T C/D regs (packed pairs) are a
//   valid PV A-fragment with no LDS round-trip.
// ---------------------------------------------------------------------------

typedef __attribute__((ext_vector_type(8))) _Float16 half8;   // 4 VGPR
typedef __attribute__((ext_vector_type(2))) __fp16 fp16x2;    // cvt_pkrtz ret
typedef __attribute__((ext_vector_type(4))) float floatx4;
typedef unsigned short u16;
typedef unsigned int u32;

#define LOG2E 1.4426950408889634f
#define TS 16         // train splits (gridDim.y of k_main)

// ------------------------------- prep --------------------------------------
// 64 blocks x 256 threads:
//  (a) permuted f16 V-frags (16 elems/thread)
//  (b) W1f/W2f f16 frag conversion (1 elem/thread, dst-coalesced)
//  (c) zero acc[8192*16] (8 floats/thread)
__global__ __launch_bounds__(256) void k_prep(
    const float* __restrict__ W1, const float* __restrict__ W2,
    const int* __restrict__ y, u16* __restrict__ W1f, u16* __restrict__ W2f,
    u16* __restrict__ Vf, float* __restrict__ acc)
{
    const int tid16 = blockIdx.x * 256 + threadIdx.x;   // 0..16383

    // ---- (a) V: elems e in [tid16*16, +16). All 16 share quad/f32 and the
    // same 8 trains; first 8 have class n0, next 8 class n0+1.
    {
        const int e0   = tid16 * 16;
        const int f32  = e0 >> 9;
        const int l0   = (e0 >> 3) & 63;          // even
        const int quad = l0 >> 4;
        const int n0   = l0 & 15;
        int yv[8];
        #pragma unroll
        for (int r = 0; r < 4; r++) {
            yv[r]     = y[f32 * 32 + quad * 4 + r];
            yv[4 + r] = y[f32 * 32 + 16 + quad * 4 + r];
        }
        half8 v0, v1;
        #pragma unroll
        for (int j = 0; j < 8; j++) {
            v0[j] = (n0     == yv[j] || n0     == 10) ? (_Float16)1.0f : (_Float16)0.0f;
            v1[j] = (n0 + 1 == yv[j] || n0 + 1 == 10) ? (_Float16)1.0f : (_Float16)0.0f;
        }
        *(half8*)(Vf + e0)     = v0;
        *(half8*)(Vf + e0 + 8) = v1;
    }

    // ---- (b) W frags: one elem per thread, enumerate by destination.
    {
        const int idx = tid16;
        if (idx < 8192) {
            int e = idx, fid = e >> 9, l = (e >> 3) & 63, jj = e & 7;
            int n1 = (fid >> 1) * 16 + (l & 15);
            int k1 = (fid & 1) * 32 + (l >> 4) * 8 + jj;
            ((_Float16*)W1f)[e] = (_Float16)W1[k1 * 128 + n1];
        } else {
            int e = idx - 8192, fid = e >> 9, l = (e >> 3) & 63, jj = e & 7;
            int n2 = (fid >> 2) * 16 + (l & 15);
            int k2 = (fid & 3) * 32 + (l >> 4) * 8 + jj;
            ((_Float16*)W2f)[e] = (_Float16)W2[k2 * 64 + n2];
        }
    }

    // ---- (c) zero acc
    {
        floatx4 z = {0.f, 0.f, 0.f, 0.f};
        floatx4* p = (floatx4*)(acc + tid16 * 8);
        p[0] = z; p[1] = z;
    }
}

// ------------------------------- embed -------------------------------------
#define HSTR 136   // 128 + 8 pad f16, rows 272B (16B multiple)

__global__ __launch_bounds__(256) void k_embed(
    const float* __restrict__ X, const float* __restrict__ Xtr,
    const u16* __restrict__ W1f, const float* __restrict__ b1,
    const u16* __restrict__ W2f, const float* __restrict__ b2,
    u16* __restrict__ Etf, u16* __restrict__ Etrf)
{
    __shared__ __align__(16) _Float16 Hbuf[4][16][HSTR];
    const int w = threadIdx.x >> 6, lane = threadIdx.x & 63;
    const int m = lane & 15, g = lane >> 4;
    const int strip = blockIdx.x * 4 + w;        // 0..1535, 16 rows each
    const int row0  = strip * 16;
    const bool isTest = (row0 < 8192);
    const float* src = isTest ? (X + (size_t)row0 * 64)
                              : (Xtr + (size_t)(row0 - 8192) * 64);
    const floatx4 fz = {0.f, 0.f, 0.f, 0.f};

    // A-frags for this lane's row (m): A[m][k = g*8+j (+32 for a1)]
    const float* prow = src + m * 64;
    half8 a0, a1;
    {
        floatx4 x0 = *(const floatx4*)(prow + g * 8);
        floatx4 x1 = *(const floatx4*)(prow + g * 8 + 4);
        floatx4 x2 = *(const floatx4*)(prow + 32 + g * 8);
        floatx4 x3 = *(const floatx4*)(prow + 32 + g * 8 + 4);
        #pragma unroll
        for (int j = 0; j < 4; j++) {
            a0[j] = (_Float16)x0[j]; a0[4 + j] = (_Float16)x1[j];
            a1[j] = (_Float16)x2[j]; a1[4 + j] = (_Float16)x3[j];
        }
    }

    // GEMM1: H[16x128] = relu(A @ W1 + b1) -> private LDS (f16)
    #pragma unroll
    for (int nt = 0; nt < 8; nt++) {
        half8 bw0 = *(const half8*)(W1f + (nt * 2 + 0) * 512 + lane * 8);
        half8 bw1 = *(const half8*)(W1f + (nt * 2 + 1) * 512 + lane * 8);
        floatx4 acc = __builtin_amdgcn_mfma_f32_16x16x32_f16(a0, bw0, fz, 0, 0, 0);
        acc = __builtin_amdgcn_mfma_f32_16x16x32_f16(a1, bw1, acc, 0, 0, 0);
        float bias = b1[nt * 16 + m];
        #pragma unroll
        for (int r = 0; r < 4; r++) {
            float h = acc[r] + bias;
            h = h > 0.f ? h : 0.f;
            Hbuf[w][g * 4 + r][nt * 16 + m] = (_Float16)h;  // C/D: row=g*4+r
        }
    }

    // GEMM2: E[16x64] = H @ W2 + b2   (A-frags from private LDS)
    half8 ha[4];
    #pragma unroll
    for (int kt = 0; kt < 4; kt++)
        ha[kt] = *(const half8*)(&Hbuf[w][m][kt * 32 + g * 8]);

    float ef[4][4];   // [nt][r]
    #pragma unroll
    for (int nt = 0; nt < 4; nt++) {
        floatx4 acc = fz;
        #pragma unroll
        for (int kt = 0; kt < 4; kt++) {
            half8 bw = *(const half8*)(W2f + (nt * 4 + kt) * 512 + lane * 8);
            acc = __builtin_amdgcn_mfma_f32_16x16x32_f16(ha[kt], bw, acc, 0, 0, 0);
        }
        float bias = b2[nt * 16 + m];
        #pragma unroll
        for (int r = 0; r < 4; r++) ef[nt][r] = acc[r] + bias;
    }

    // Row norms (16-lane butterfly); log2(e) folded into the test side.
    const float sc = isTest ? LOG2E : 1.0f;
    float rn[4];
    #pragma unroll
    for (int r = 0; r < 4; r++) {
        float ss = 0.f;
        #pragma unroll
        for (int nt = 0; nt < 4; nt++) ss += ef[nt][r] * ef[nt][r];
        ss += __shfl_xor(ss, 1);
        ss += __shfl_xor(ss, 2);
        ss += __shfl_xor(ss, 4);
        ss += __shfl_xor(ss, 8);
        rn[r] = rsqrtf(fmaxf(ss, 1e-30f)) * sc;
    }

    // Store normalized f16 embedding in frag-ready layout
    u16* dst = isTest ? Etf : Etrf;
    const int stile = (isTest ? row0 : row0 - 8192) >> 4;
    #pragma unroll
    for (int nt = 0; nt < 4; nt++) {
        int col = nt * 16 + m;
        int kt = col >> 5, gg = (col >> 3) & 3, jj = col & 7;
        #pragma unroll
        for (int r = 0; r < 4; r++) {
            int rloc = g * 4 + r;
            ((_Float16*)dst)[(stile * 2 + kt) * 512 + (gg * 16 + rloc) * 8 + jj] =
                (_Float16)(ef[nt][r] * rn[r]);
        }
    }
}

// ------------------------------- main --------------------------------------
// TM=64 test rows/block (4 subtiles), TS=16 train splits. Per wave: 256
// trains = 8 groups of 32. 12 waves/CU via launch_bounds(256,3).
__global__ __launch_bounds__(256, 3) void k_main(
    const u16* __restrict__ Etf, const u16* __restrict__ Etrf,
    const u16* __restrict__ Vf, float* __restrict__ acc)
{
    __shared__ float Obuf[4][64][16];           // 16 KB
    const int w = threadIdx.x >> 6, lane = threadIdx.x & 63;
    const int m = lane & 15, g = lane >> 4;
    const int bx = blockIdx.x, by = blockIdx.y;
    const floatx4 fz = {0.f, 0.f, 0.f, 0.f};

    // Resident TEST fragments (B-operand of the S^T MFMA): 4 subtiles x 2
    half8 b[4][2];
    #pragma unroll
    for (int ns = 0; ns < 4; ns++) {
        int stile = bx * 4 + ns;
        b[ns][0] = *(const half8*)(Etf + (stile * 2 + 0) * 512 + lane * 8);
        b[ns][1] = *(const half8*)(Etf + (stile * 2 + 1) * 512 + lane * 8);
    }

    floatx4 o[4] = {fz, fz, fz, fz};
    const int wstart = by * 1024 + w * 256;     // this wave's train slice

    for (int g32 = 0; g32 < 8; g32++) {         // 32 trains per group
        const int t32 = wstart + g32 * 32;
        // frag index of tile (t32/16) is t32>>3  (frag = tile*2)  [R3 bugfix]
        const u16* etr = Etrf + (size_t)(t32 >> 3) * 512 + lane * 8;
        half8 a0 = *(const half8*)(etr);
        half8 a1 = *(const half8*)(etr + 512);
        half8 a2 = *(const half8*)(etr + 1024);
        half8 a3 = *(const half8*)(etr + 1536);
        half8 vf = *(const half8*)(Vf + (size_t)(t32 >> 5) * 512 + lane * 8);

        #pragma unroll
        for (int ns = 0; ns < 4; ns++) {
            // S^T for two 16-train tiles: C/D row=train(g*4+r), col=test(m)
            floatx4 s0 = __builtin_amdgcn_mfma_f32_16x16x32_f16(a0, b[ns][0], fz, 0, 0, 0);
            s0 = __builtin_amdgcn_mfma_f32_16x16x32_f16(a1, b[ns][1], s0, 0, 0, 0);
            floatx4 s1 = __builtin_amdgcn_mfma_f32_16x16x32_f16(a2, b[ns][0], fz, 0, 0, 0);
            s1 = __builtin_amdgcn_mfma_f32_16x16x32_f16(a3, b[ns][1], s1, 0, 0, 0);
            // p = 2^s (log2e folded into test embd); pack to f16 pairs
            float p0 = __builtin_amdgcn_exp2f(s0[0]);
            float p1 = __builtin_amdgcn_exp2f(s0[1]);
            float p2 = __builtin_amdgcn_exp2f(s0[2]);
            float p3 = __builtin_amdgcn_exp2f(s0[3]);
            float p4 = __builtin_amdgcn_exp2f(s1[0]);
            float p5 = __builtin_amdgcn_exp2f(s1[1]);
            float p6 = __builtin_amdgcn_exp2f(s1[2]);
            float p7 = __builtin_amdgcn_exp2f(s1[3]);
            union { fp16x2 h2[4]; half8 h8; } P;
            P.h2[0] = __builtin_amdgcn_cvt_pkrtz(p0, p1);
            P.h2[1] = __builtin_amdgcn_cvt_pkrtz(p2, p3);
            P.h2[2] = __builtin_amdgcn_cvt_pkrtz(p4, p5);
            P.h2[3] = __builtin_amdgcn_cvt_pkrtz(p6, p7);
            // pa[j] holds train tau(quad,j) -> matches permuted Vf
            o[ns] = __builtin_amdgcn_mfma_f32_16x16x32_f16(P.h8, vf, o[ns], 0, 0, 0);
        }
    }

    // Combine 4 waves in LDS, then one atomicAdd per (row,class)
    #pragma unroll
    for (int ms = 0; ms < 4; ms++)
        #pragma unroll
        for (int r = 0; r < 4; r++)
            Obuf[w][ms * 16 + g * 4 + r][m] = o[ms][r];
    __syncthreads();
    for (int i = threadIdx.x; i < 1024; i += 256) {
        int mm = i >> 4, c = i & 15;
        float s = Obuf[0][mm][c] + Obuf[1][mm][c] + Obuf[2][mm][c] + Obuf[3][mm][c];
        atomicAdd(&acc[(bx * 64 + mm) * 16 + c], s);
    }
}

// ------------------------------- final -------------------------------------
__global__ __launch_bounds__(256) void k_final(
    const float* __restrict__ acc, float* __restrict__ out)
{
    int row = blockIdx.x * 256 + threadIdx.x;
    if (row < 8192) {
        const floatx4* src = (const floatx4*)(acc + (size_t)row * 16);
        floatx4 s0 = src[0], s1 = src[1], s2 = src[2];
        float inv = 1.0f / s2[2];               // col 10 = denominator
        out[row * 10 + 0] = s0[0] * inv;
        out[row * 10 + 1] = s0[1] * inv;
        out[row * 10 + 2] = s0[2] * inv;
        out[row * 10 + 3] = s0[3] * inv;
        out[row * 10 + 4] = s1[0] * inv;
        out[row * 10 + 5] = s1[1] * inv;
        out[row * 10 + 6] = s1[2] * inv;
        out[row * 10 + 7] = s1[3] * inv;
        out[row * 10 + 8] = s2[0] * inv;
        out[row * 10 + 9] = s2[1] * inv;
    }
}

// ------------------------------ launcher -----------------------------------
extern "C" void kernel_launch(void* const* d_in, const int* in_sizes, int n_in,
                              void* d_out, int out_size, void* d_ws, size_t ws_size,
                              hipStream_t stream)
{
    const float* X   = (const float*)d_in[0];   // [8192,64]
    const float* Xtr = (const float*)d_in[1];   // [16384,64]
    const int*   y   = (const int*)d_in[2];     // [16384]
    const float* W1  = (const float*)d_in[3];   // [64,128]
    const float* b1  = (const float*)d_in[4];   // [128]
    const float* W2  = (const float*)d_in[5];   // [128,64]
    const float* b2  = (const float*)d_in[6];   // [64]
    float* out = (float*)d_out;                 // [8192,10]

    char* ws = (char*)d_ws;
    float* acc = (float*)ws;                                    // 512 KB
    u16* Etf  = (u16*)(ws + 524288);                            // 1 MB
    u16* Etrf = (u16*)(ws + 524288 + 1048576);                  // 2 MB
    u16* Vf   = (u16*)(ws + 524288 + 1048576 + 2097152);        // 512 KB
    u16* W1f  = (u16*)(ws + 524288 + 1048576 + 2097152 + 524288);  // 16 KB
    u16* W2f  = W1f + 8192;                                     // 16 KB

    k_prep<<<64, 256, 0, stream>>>(W1, W2, y, W1f, W2f, Vf, acc);
    k_embed<<<384, 256, 0, stream>>>(X, Xtr, W1f, b1, W2f, b2, Etf, Etrf);
    k_main<<<dim3(128, TS), 256, 0, stream>>>(Etf, Etrf, Vf, acc);
    k_final<<<32, 256, 0, stream>>>(acc, out);
}

// Round 6
// 100.379 us; speedup vs baseline: 1.0066x; 1.0066x over previous
//
#include <hip/hip_runtime.h>
#include <hip/hip_bf16.h>

// ---------------------------------------------------------------------------
// preds[i][c] = sum_j exp(cos(e_i, t_j)) [y_j==c]  /  sum_j exp(cos(e_i, t_j))
// where e = normalize(mlp(X)), t = normalize(mlp(x_train)).
// exp needs no max-subtraction: cosine <= 1 so exp(s) <= e.
//
// R6 = R5 hot-loop + R3's two structural wins, correctly indexed:
//  * TM=128 test rows/block (bx=64): halves Etrf L2 traffic (256->128 MB)
//    and halves block count (1024) -> half the atomics/output work.
//  * Explicit register prefetch of the next 32-train group (5 frags) so the
//    dependent L2 latency (~200-300 cyc) is hidden behind the 40 MFMAs +
//    64 exp2 of the current group.
//  * Keeps: f16 pipeline, direct-feed PV (no LDS in hot loop), frag index
//    = t32>>3 (R4 bugfix), launch_bounds(256,3).
//
// Frag-ready layout for an f16 matrix M[row][k] (16-row tiles, K=64):
//   elem(row,k) at ((row>>4)*2 + (k>>5))*512 + (((k>>3)&3)*16 + (row&15))*8
//                + (k&7);  one frag = 512 elems; load = dwordx4 at lane*8.
//   Serves both A-operands (row=M) and B-operands (row=N).
// PV direct-feed permutation: V stored with k-index tau(quad,j) =
//   (j>>2)*16 + quad*4 + (j&3) so the S^T C/D regs (packed pairs) are a
//   valid PV A-fragment with no LDS round-trip.
// ---------------------------------------------------------------------------

typedef __attribute__((ext_vector_type(8))) _Float16 half8;   // 4 VGPR
typedef __attribute__((ext_vector_type(2))) __fp16 fp16x2;    // cvt_pkrtz ret
typedef __attribute__((ext_vector_type(4))) float floatx4;
typedef unsigned short u16;
typedef unsigned int u32;

#define LOG2E 1.4426950408889634f
#define TS 16         // train splits (gridDim.y of k_main)

// ------------------------------- prep --------------------------------------
// 64 blocks x 256 threads:
//  (a) permuted f16 V-frags (16 elems/thread)
//  (b) W1f/W2f f16 frag conversion (1 elem/thread, dst-coalesced)
//  (c) zero acc[8192*16] (8 floats/thread)
__global__ __launch_bounds__(256) void k_prep(
    const float* __restrict__ W1, const float* __restrict__ W2,
    const int* __restrict__ y, u16* __restrict__ W1f, u16* __restrict__ W2f,
    u16* __restrict__ Vf, float* __restrict__ acc)
{
    const int tid16 = blockIdx.x * 256 + threadIdx.x;   // 0..16383

    // ---- (a) V: elems e in [tid16*16, +16). All 16 share quad/f32 and the
    // same 8 trains; first 8 have class n0, next 8 class n0+1.
    {
        const int e0   = tid16 * 16;
        const int f32  = e0 >> 9;
        const int l0   = (e0 >> 3) & 63;          // even
        const int quad = l0 >> 4;
        const int n0   = l0 & 15;
        int yv[8];
        #pragma unroll
        for (int r = 0; r < 4; r++) {
            yv[r]     = y[f32 * 32 + quad * 4 + r];
            yv[4 + r] = y[f32 * 32 + 16 + quad * 4 + r];
        }
        half8 v0, v1;
        #pragma unroll
        for (int j = 0; j < 8; j++) {
            v0[j] = (n0     == yv[j] || n0     == 10) ? (_Float16)1.0f : (_Float16)0.0f;
            v1[j] = (n0 + 1 == yv[j] || n0 + 1 == 10) ? (_Float16)1.0f : (_Float16)0.0f;
        }
        *(half8*)(Vf + e0)     = v0;
        *(half8*)(Vf + e0 + 8) = v1;
    }

    // ---- (b) W frags: one elem per thread, enumerate by destination.
    {
        const int idx = tid16;
        if (idx < 8192) {
            int e = idx, fid = e >> 9, l = (e >> 3) & 63, jj = e & 7;
            int n1 = (fid >> 1) * 16 + (l & 15);
            int k1 = (fid & 1) * 32 + (l >> 4) * 8 + jj;
            ((_Float16*)W1f)[e] = (_Float16)W1[k1 * 128 + n1];
        } else {
            int e = idx - 8192, fid = e >> 9, l = (e >> 3) & 63, jj = e & 7;
            int n2 = (fid >> 2) * 16 + (l & 15);
            int k2 = (fid & 3) * 32 + (l >> 4) * 8 + jj;
            ((_Float16*)W2f)[e] = (_Float16)W2[k2 * 64 + n2];
        }
    }

    // ---- (c) zero acc
    {
        floatx4 z = {0.f, 0.f, 0.f, 0.f};
        floatx4* p = (floatx4*)(acc + tid16 * 8);
        p[0] = z; p[1] = z;
    }
}

// ------------------------------- embed -------------------------------------
#define HSTR 136   // 128 + 8 pad f16, rows 272B (16B multiple)

__global__ __launch_bounds__(256) void k_embed(
    const float* __restrict__ X, const float* __restrict__ Xtr,
    const u16* __restrict__ W1f, const float* __restrict__ b1,
    const u16* __restrict__ W2f, const float* __restrict__ b2,
    u16* __restrict__ Etf, u16* __restrict__ Etrf)
{
    __shared__ __align__(16) _Float16 Hbuf[4][16][HSTR];
    const int w = threadIdx.x >> 6, lane = threadIdx.x & 63;
    const int m = lane & 15, g = lane >> 4;
    const int strip = blockIdx.x * 4 + w;        // 0..1535, 16 rows each
    const int row0  = strip * 16;
    const bool isTest = (row0 < 8192);
    const float* src = isTest ? (X + (size_t)row0 * 64)
                              : (Xtr + (size_t)(row0 - 8192) * 64);
    const floatx4 fz = {0.f, 0.f, 0.f, 0.f};

    // A-frags for this lane's row (m): A[m][k = g*8+j (+32 for a1)]
    const float* prow = src + m * 64;
    half8 a0, a1;
    {
        floatx4 x0 = *(const floatx4*)(prow + g * 8);
        floatx4 x1 = *(const floatx4*)(prow + g * 8 + 4);
        floatx4 x2 = *(const floatx4*)(prow + 32 + g * 8);
        floatx4 x3 = *(const floatx4*)(prow + 32 + g * 8 + 4);
        #pragma unroll
        for (int j = 0; j < 4; j++) {
            a0[j] = (_Float16)x0[j]; a0[4 + j] = (_Float16)x1[j];
            a1[j] = (_Float16)x2[j]; a1[4 + j] = (_Float16)x3[j];
        }
    }

    // GEMM1: H[16x128] = relu(A @ W1 + b1) -> private LDS (f16)
    #pragma unroll
    for (int nt = 0; nt < 8; nt++) {
        half8 bw0 = *(const half8*)(W1f + (nt * 2 + 0) * 512 + lane * 8);
        half8 bw1 = *(const half8*)(W1f + (nt * 2 + 1) * 512 + lane * 8);
        floatx4 acc = __builtin_amdgcn_mfma_f32_16x16x32_f16(a0, bw0, fz, 0, 0, 0);
        acc = __builtin_amdgcn_mfma_f32_16x16x32_f16(a1, bw1, acc, 0, 0, 0);
        float bias = b1[nt * 16 + m];
        #pragma unroll
        for (int r = 0; r < 4; r++) {
            float h = acc[r] + bias;
            h = h > 0.f ? h : 0.f;
            Hbuf[w][g * 4 + r][nt * 16 + m] = (_Float16)h;  // C/D: row=g*4+r
        }
    }

    // GEMM2: E[16x64] = H @ W2 + b2   (A-frags from private LDS)
    half8 ha[4];
    #pragma unroll
    for (int kt = 0; kt < 4; kt++)
        ha[kt] = *(const half8*)(&Hbuf[w][m][kt * 32 + g * 8]);

    float ef[4][4];   // [nt][r]
    #pragma unroll
    for (int nt = 0; nt < 4; nt++) {
        floatx4 acc = fz;
        #pragma unroll
        for (int kt = 0; kt < 4; kt++) {
            half8 bw = *(const half8*)(W2f + (nt * 4 + kt) * 512 + lane * 8);
            acc = __builtin_amdgcn_mfma_f32_16x16x32_f16(ha[kt], bw, acc, 0, 0, 0);
        }
        float bias = b2[nt * 16 + m];
        #pragma unroll
        for (int r = 0; r < 4; r++) ef[nt][r] = acc[r] + bias;
    }

    // Row norms (16-lane butterfly); log2(e) folded into the test side.
    const float sc = isTest ? LOG2E : 1.0f;
    float rn[4];
    #pragma unroll
    for (int r = 0; r < 4; r++) {
        float ss = 0.f;
        #pragma unroll
        for (int nt = 0; nt < 4; nt++) ss += ef[nt][r] * ef[nt][r];
        ss += __shfl_xor(ss, 1);
        ss += __shfl_xor(ss, 2);
        ss += __shfl_xor(ss, 4);
        ss += __shfl_xor(ss, 8);
        rn[r] = rsqrtf(fmaxf(ss, 1e-30f)) * sc;
    }

    // Store normalized f16 embedding in frag-ready layout
    u16* dst = isTest ? Etf : Etrf;
    const int stile = (isTest ? row0 : row0 - 8192) >> 4;
    #pragma unroll
    for (int nt = 0; nt < 4; nt++) {
        int col = nt * 16 + m;
        int kt = col >> 5, gg = (col >> 3) & 3, jj = col & 7;
        #pragma unroll
        for (int r = 0; r < 4; r++) {
            int rloc = g * 4 + r;
            ((_Float16*)dst)[(stile * 2 + kt) * 512 + (gg * 16 + rloc) * 8 + jj] =
                (_Float16)(ef[nt][r] * rn[r]);
        }
    }
}

// ------------------------------- main --------------------------------------
// TM=128 test rows/block (8 subtiles), TS=16 train splits, grid 64x16=1024
// blocks. Per wave: 256 trains = 8 groups of 32, with next-group register
// prefetch. launch_bounds(256,3) -> <=168 VGPR, 12 waves/CU.
__global__ __launch_bounds__(256, 3) void k_main(
    const u16* __restrict__ Etf, const u16* __restrict__ Etrf,
    const u16* __restrict__ Vf, float* __restrict__ acc)
{
    __shared__ float Obuf[4][128][16];          // 32 KB
    const int w = threadIdx.x >> 6, lane = threadIdx.x & 63;
    const int m = lane & 15, g = lane >> 4;
    const int bx = blockIdx.x, by = blockIdx.y;
    const floatx4 fz = {0.f, 0.f, 0.f, 0.f};

    // Resident TEST fragments (B-operand of the S^T MFMA): 8 subtiles x 2
    half8 b[8][2];
    #pragma unroll
    for (int ns = 0; ns < 8; ns++) {
        int stile = bx * 8 + ns;
        b[ns][0] = *(const half8*)(Etf + (stile * 2 + 0) * 512 + lane * 8);
        b[ns][1] = *(const half8*)(Etf + (stile * 2 + 1) * 512 + lane * 8);
    }

    floatx4 o[8] = {fz, fz, fz, fz, fz, fz, fz, fz};
    const int wstart = by * 1024 + w * 256;     // this wave's train slice

    // Prefetch group 0 (frag idx = t32>>3, vfrag idx = t32>>5)
    const u16* e0p = Etrf + (size_t)(wstart >> 3) * 512 + lane * 8;
    half8 a0 = *(const half8*)(e0p);
    half8 a1 = *(const half8*)(e0p + 512);
    half8 a2 = *(const half8*)(e0p + 1024);
    half8 a3 = *(const half8*)(e0p + 1536);
    half8 vf = *(const half8*)(Vf + (size_t)(wstart >> 5) * 512 + lane * 8);

    for (int g32 = 0; g32 < 8; g32++) {         // 32 trains per group
        // prefetch next group (clamped on last iter; redundant reload ok)
        const int gn  = (g32 < 7) ? g32 + 1 : 7;
        const int t32n = wstart + gn * 32;
        const u16* enp = Etrf + (size_t)(t32n >> 3) * 512 + lane * 8;
        half8 na0 = *(const half8*)(enp);
        half8 na1 = *(const half8*)(enp + 512);
        half8 na2 = *(const half8*)(enp + 1024);
        half8 na3 = *(const half8*)(enp + 1536);
        half8 nvf = *(const half8*)(Vf + (size_t)(t32n >> 5) * 512 + lane * 8);

        #pragma unroll
        for (int ns = 0; ns < 8; ns++) {
            // S^T for two 16-train tiles: C/D row=train(g*4+r), col=test(m)
            floatx4 s0 = __builtin_amdgcn_mfma_f32_16x16x32_f16(a0, b[ns][0], fz, 0, 0, 0);
            s0 = __builtin_amdgcn_mfma_f32_16x16x32_f16(a1, b[ns][1], s0, 0, 0, 0);
            floatx4 s1 = __builtin_amdgcn_mfma_f32_16x16x32_f16(a2, b[ns][0], fz, 0, 0, 0);
            s1 = __builtin_amdgcn_mfma_f32_16x16x32_f16(a3, b[ns][1], s1, 0, 0, 0);
            // p = 2^s (log2e folded into test embd); pack to f16 pairs
            float p0 = __builtin_amdgcn_exp2f(s0[0]);
            float p1 = __builtin_amdgcn_exp2f(s0[1]);
            float p2 = __builtin_amdgcn_exp2f(s0[2]);
            float p3 = __builtin_amdgcn_exp2f(s0[3]);
            float p4 = __builtin_amdgcn_exp2f(s1[0]);
            float p5 = __builtin_amdgcn_exp2f(s1[1]);
            float p6 = __builtin_amdgcn_exp2f(s1[2]);
            float p7 = __builtin_amdgcn_exp2f(s1[3]);
            union { fp16x2 h2[4]; half8 h8; } P;
            P.h2[0] = __builtin_amdgcn_cvt_pkrtz(p0, p1);
            P.h2[1] = __builtin_amdgcn_cvt_pkrtz(p2, p3);
            P.h2[2] = __builtin_amdgcn_cvt_pkrtz(p4, p5);
            P.h2[3] = __builtin_amdgcn_cvt_pkrtz(p6, p7);
            // pa[j] holds train tau(quad,j) -> matches permuted Vf
            o[ns] = __builtin_amdgcn_mfma_f32_16x16x32_f16(P.h8, vf, o[ns], 0, 0, 0);
        }
        a0 = na0; a1 = na1; a2 = na2; a3 = na3; vf = nvf;
    }

    // Combine 4 waves in LDS, then one atomicAdd per (row,class)
    #pragma unroll
    for (int ms = 0; ms < 8; ms++)
        #pragma unroll
        for (int r = 0; r < 4; r++)
            Obuf[w][ms * 16 + g * 4 + r][m] = o[ms][r];
    __syncthreads();
    for (int i = threadIdx.x; i < 2048; i += 256) {
        int mm = i >> 4, c = i & 15;
        float s = Obuf[0][mm][c] + Obuf[1][mm][c] + Obuf[2][mm][c] + Obuf[3][mm][c];
        atomicAdd(&acc[(bx * 128 + mm) * 16 + c], s);
    }
}

// ------------------------------- final -------------------------------------
__global__ __launch_bounds__(256) void k_final(
    const float* __restrict__ acc, float* __restrict__ out)
{
    int row = blockIdx.x * 256 + threadIdx.x;
    if (row < 8192) {
        const floatx4* src = (const floatx4*)(acc + (size_t)row * 16);
        floatx4 s0 = src[0], s1 = src[1], s2 = src[2];
        float inv = 1.0f / s2[2];               // col 10 = denominator
        out[row * 10 + 0] = s0[0] * inv;
        out[row * 10 + 1] = s0[1] * inv;
        out[row * 10 + 2] = s0[2] * inv;
        out[row * 10 + 3] = s0[3] * inv;
        out[row * 10 + 4] = s1[0] * inv;
        out[row * 10 + 5] = s1[1] * inv;
        out[row * 10 + 6] = s1[2] * inv;
        out[row * 10 + 7] = s1[3] * inv;
        out[row * 10 + 8] = s2[0] * inv;
        out[row * 10 + 9] = s2[1] * inv;
    }
}

// ------------------------------ launcher -----------------------------------
extern "C" void kernel_launch(void* const* d_in, const int* in_sizes, int n_in,
                              void* d_out, int out_size, void* d_ws, size_t ws_size,
                              hipStream_t stream)
{
    const float* X   = (const float*)d_in[0];   // [8192,64]
    const float* Xtr = (const float*)d_in[1];   // [16384,64]
    const int*   y   = (const int*)d_in[2];     // [16384]
    const float* W1  = (const float*)d_in[3];   // [64,128]
    const float* b1  = (const float*)d_in[4];   // [128]
    const float* W2  = (const float*)d_in[5];   // [128,64]
    const float* b2  = (const float*)d_in[6];   // [64]
    float* out = (float*)d_out;                 // [8192,10]

    char* ws = (char*)d_ws;
    float* acc = (float*)ws;                                    // 512 KB
    u16* Etf  = (u16*)(ws + 524288);                            // 1 MB
    u16* Etrf = (u16*)(ws + 524288 + 1048576);                  // 2 MB
    u16* Vf   = (u16*)(ws + 524288 + 1048576 + 2097152);        // 512 KB
    u16* W1f  = (u16*)(ws + 524288 + 1048576 + 2097152 + 524288);  // 16 KB
    u16* W2f  = W1f + 8192;                                     // 16 KB

    k_prep<<<64, 256, 0, stream>>>(W1, W2, y, W1f, W2f, Vf, acc);
    k_embed<<<384, 256, 0, stream>>>(X, Xtr, W1f, b1, W2f, b2, Etf, Etrf);
    k_main<<<dim3(64, TS), 256, 0, stream>>>(Etf, Etrf, Vf, acc);
    k_final<<<32, 256, 0, stream>>>(acc, out);
}